// Round 1
// baseline (1330.035 us; speedup 1.0000x reference)
//
#include <hip/hip_runtime.h>
#include <hip/hip_bf16.h>

// Sparse graph-attention Gumbel mask.
//
// Restructuring: with M = Wq^T Wk [E,E],
//   w_ui[e] = adj*( Xu[r]·C[c] + t1[r] + u1[c] + c0 ),  C = Xi M^T
//   w_iu[e] = adj*( Xu[r]·D[c] + t2[r] + u2[c] + c0 ),  D = Xi M
// so the per-edge gather is Xu[r] (512B) + CD[c] (1KB) instead of 2KB of
// projected rows. t*/u*/c0 are bias-fold scalars (zero for this instance,
// implemented for generality).

#define EMB 128
#define TAUINV 2.0f

__device__ __forceinline__ unsigned fkey(float f) {
    unsigned u = __float_as_uint(f);
    return (u & 0x80000000u) ? ~u : (u | 0x80000000u);
}
__device__ __forceinline__ float fdecode(unsigned u) {
    return __uint_as_float((u & 0x80000000u) ? (u ^ 0x80000000u) : ~u);
}

// ---- kernel 1: BIGM[k][j] (j<128: M[j][k]; j>=128: M[k][j-128]), v1, v2, c0
__global__ void k_prep(const float* __restrict__ Wq, const float* __restrict__ Wk,
                       const float* __restrict__ bq, const float* __restrict__ bk,
                       float* __restrict__ BIGM, float* __restrict__ v1,
                       float* __restrict__ v2, float* __restrict__ c0) {
    int e1 = blockIdx.x, e2 = threadIdx.x;
    float acc = 0.f;
    for (int a = 0; a < EMB; ++a) acc += Wq[a * EMB + e1] * Wk[a * EMB + e2];
    // M[e1][e2] = acc
    BIGM[e2 * 256 + e1] = acc;            // BIGM[k=e2][j=e1] = M[j][k]
    BIGM[e1 * 256 + 128 + e2] = acc;      // BIGM[k=e1][128+e2] = M[k][e2]
    if (e2 == 0) { float s = 0.f; for (int a = 0; a < EMB; ++a) s += Wq[a * EMB + e1] * bk[a]; v1[e1] = s; }
    if (e2 == 1) { float s = 0.f; for (int a = 0; a < EMB; ++a) s += Wk[a * EMB + e1] * bq[a]; v2[e1] = s; }
    if (e1 == 0 && e2 == 2) { float s = 0.f; for (int a = 0; a < EMB; ++a) s += bq[a] * bk[a]; *c0 = s; }
}

// ---- kernel 2: CD[m][half*128 + c] = sum_k Xi[m][k] * BIGM[k][half*128 + c]
__global__ __launch_bounds__(256) void k_cd(const float* __restrict__ Xi,
                                            const float* __restrict__ BIGM,
                                            float* __restrict__ CD, int nItems) {
    __shared__ float Xs[32 * 128];
    __shared__ float Ms[128 * 128];
    const int m0 = blockIdx.x * 32;
    const int half = blockIdx.y;
    const int t = threadIdx.x;

    float4* Ms4 = (float4*)Ms;
    const float4* BG4 = (const float4*)BIGM;
    for (int idx = t; idx < 128 * 32; idx += 256) {
        int k = idx >> 5, c4 = idx & 31;
        Ms4[k * 32 + c4] = BG4[k * 64 + half * 32 + c4];
    }
    float4* Xs4 = (float4*)Xs;
    const float4* Xi4 = (const float4*)Xi;
    for (int idx = t; idx < 32 * 32; idx += 256) {
        int rr = idx >> 5, c4 = idx & 31;
        int row = m0 + rr;
        Xs4[idx] = (row < nItems) ? Xi4[(size_t)row * 32 + c4] : make_float4(0.f, 0.f, 0.f, 0.f);
    }
    __syncthreads();

    const int rg = t >> 5, cg = t & 31;
    float acc[4][4] = {};
    for (int k = 0; k < 128; k += 4) {
        float4 xv[4], wv[4];
#pragma unroll
        for (int i = 0; i < 4; ++i) xv[i] = Xs4[(rg * 4 + i) * 32 + (k >> 2)];
#pragma unroll
        for (int kk = 0; kk < 4; ++kk) wv[kk] = Ms4[(k + kk) * 32 + cg];
#pragma unroll
        for (int kk = 0; kk < 4; ++kk) {
            float w0 = wv[kk].x, w1 = wv[kk].y, w2 = wv[kk].z, w3 = wv[kk].w;
#pragma unroll
            for (int i = 0; i < 4; ++i) {
                float x = (kk == 0) ? xv[i].x : (kk == 1) ? xv[i].y : (kk == 2) ? xv[i].z : xv[i].w;
                acc[i][0] += x * w0; acc[i][1] += x * w1; acc[i][2] += x * w2; acc[i][3] += x * w3;
            }
        }
    }
#pragma unroll
    for (int i = 0; i < 4; ++i) {
        int row = m0 + rg * 4 + i;
        if (row < nItems) {
            float4 v = make_float4(acc[i][0], acc[i][1], acc[i][2], acc[i][3]);
            ((float4*)(CD + (size_t)row * 256 + half * 128))[cg] = v;
        }
    }
}

// ---- kernel 3: o1[g] = X[g]·a, o2[g] = X[g]·b (32 lanes per row)
__global__ void k_rowdot(const float* __restrict__ X, int n,
                         const float* __restrict__ a, const float* __restrict__ b,
                         float* __restrict__ o1, float* __restrict__ o2) {
    int g = blockIdx.x * 8 + (threadIdx.x >> 5);
    int l = threadIdx.x & 31;
    if (g >= n) return;
    float4 x = ((const float4*)(X + (size_t)g * EMB))[l];
    float4 av = ((const float4*)a)[l];
    float4 bv = ((const float4*)b)[l];
    float p1 = x.x * av.x + x.y * av.y + x.z * av.z + x.w * av.w;
    float p2 = x.x * bv.x + x.y * bv.y + x.z * bv.z + x.w * bv.w;
    for (int off = 16; off; off >>= 1) { p1 += __shfl_xor(p1, off); p2 += __shfl_xor(p2, off); }
    if (l == 0) { o1[g] = p1; o2[g] = p2; }
}

// ---- kernel 4: per-edge dots, logits, segment max (32 lanes per edge)
__global__ __launch_bounds__(256) void k_edge1(
    const float* __restrict__ Xu, const float* __restrict__ CD,
    const float* __restrict__ t1, const float* __restrict__ t2,
    const float* __restrict__ u1, const float* __restrict__ u2,
    const float* __restrict__ c0p, const float* __restrict__ adj,
    const float* __restrict__ gu1, const float* __restrict__ gu2,
    const int* __restrict__ rows, const int* __restrict__ cols,
    float* __restrict__ L1, float* __restrict__ L2,
    unsigned* __restrict__ mx1, unsigned* __restrict__ mx2, int nnz) {
    const int gid = blockIdx.x * 8 + (threadIdx.x >> 5);
    const int l = threadIdx.x & 31;
    const int stride = gridDim.x * 8;
    const float c0 = *c0p;
    for (int e = gid; e < nnz; e += stride) {
        int r = rows[e], c = cols[e];
        float4 xu = ((const float4*)(Xu + (size_t)r * EMB))[l];
        const float4* cd = (const float4*)(CD + (size_t)c * 256);
        float4 cv = cd[l];
        float4 dv = cd[32 + l];
        float p1 = xu.x * cv.x + xu.y * cv.y + xu.z * cv.z + xu.w * cv.w;
        float p2 = xu.x * dv.x + xu.y * dv.y + xu.z * dv.z + xu.w * dv.w;
        for (int off = 16; off; off >>= 1) { p1 += __shfl_xor(p1, off); p2 += __shfl_xor(p2, off); }
        if (l < 2) {
            float p = (l == 0) ? p1 : p2;
            float tt = (l == 0) ? t1[r] : t2[r];
            float uu = (l == 0) ? u1[c] : u2[c];
            float g = logf(-logf(((l == 0) ? gu1 : gu2)[e]));   // logf, not __logf: u near 1 needs relative accuracy
            float w = adj[e] * (p + tt + uu + c0);
            float lg = (w - g) * TAUINV;
            if (l == 0) { L1[e] = lg; atomicMax(mx1 + r, fkey(lg)); }
            else        { L2[e] = lg; atomicMax(mx2 + c, fkey(lg)); }
        }
    }
}

// ---- kernel 5: exp(logit - max), write out, segment sums
__global__ void k_exp(const float* __restrict__ L1, const float* __restrict__ L2,
                      const int* __restrict__ rows, const int* __restrict__ cols,
                      const unsigned* __restrict__ mx1, const unsigned* __restrict__ mx2,
                      float* __restrict__ s1, float* __restrict__ s2,
                      float* __restrict__ out, int nnz) {
    int i0 = blockIdx.x * blockDim.x + threadIdx.x;
    int stride = gridDim.x * blockDim.x;
    for (int e = i0; e < nnz; e += stride) {
        int r = rows[e], c = cols[e];
        float e1 = expf(L1[e] - fdecode(mx1[r]));
        float e2 = expf(L2[e] - fdecode(mx2[c]));
        out[e] = e1;
        out[nnz + e] = e2;
        atomicAdd(s1 + r, e1);
        atomicAdd(s2 + c, e2);
    }
}

// ---- kernel 6: normalize
__global__ void k_div(const int* __restrict__ rows, const int* __restrict__ cols,
                      const float* __restrict__ s1, const float* __restrict__ s2,
                      float* __restrict__ out, int nnz) {
    int i0 = blockIdx.x * blockDim.x + threadIdx.x;
    int stride = gridDim.x * blockDim.x;
    for (int e = i0; e < nnz; e += stride) {
        out[e] = out[e] / s1[rows[e]];
        out[nnz + e] = out[nnz + e] / s2[cols[e]];
    }
}

extern "C" void kernel_launch(void* const* d_in, const int* in_sizes, int n_in,
                              void* d_out, int out_size, void* d_ws, size_t ws_size,
                              hipStream_t stream) {
    const float* Xu  = (const float*)d_in[0];
    const float* Xi  = (const float*)d_in[1];
    const float* Wq  = (const float*)d_in[2];
    const float* bq  = (const float*)d_in[3];
    const float* Wk  = (const float*)d_in[4];
    const float* bk  = (const float*)d_in[5];
    const float* adj = (const float*)d_in[6];
    const float* gu1 = (const float*)d_in[7];
    const float* gu2 = (const float*)d_in[8];
    const int* rows  = (const int*)d_in[9];
    const int* cols  = (const int*)d_in[10];
    float* out = (float*)d_out;

    const int U   = in_sizes[0] / EMB;
    const int I   = in_sizes[1] / EMB;
    const int nnz = in_sizes[6];

    float* w = (float*)d_ws;
    float* BIGM = w;                      // 128*256
    float* v1   = BIGM + 32768;           // 128
    float* v2   = v1 + 128;               // 128
    float* c0   = v2 + 128;               // 1 (padded 64)
    float* t1   = c0 + 64;                // U
    float* t2   = t1 + U;                 // U
    float* u1   = t2 + U;                 // I
    float* u2   = u1 + I;                 // I
    float* CD   = u2 + I;                 // I*256
    float* L1   = CD + (size_t)I * 256;   // nnz
    float* L2   = L1 + nnz;               // nnz
    unsigned* mx1 = (unsigned*)(L2 + nnz);   // U
    unsigned* mx2 = mx1 + U;                 // I
    float* s1   = (float*)(mx2 + I);         // U
    float* s2   = s1 + U;                    // I
    size_t need = (size_t)((char*)(s2 + I) - (char*)d_ws);
    if (need > ws_size) return;  // insufficient workspace: fail loudly

    // zero mx1/mx2/s1/s2 (contiguous). key==0 encodes -NaN: below every real key.
    hipMemsetAsync(mx1, 0, (size_t)(2 * (U + I)) * 4, stream);

    k_prep<<<128, 128, 0, stream>>>(Wq, Wk, bq, bk, BIGM, v1, v2, c0);
    k_cd<<<dim3((I + 31) / 32, 2), 256, 0, stream>>>(Xi, BIGM, CD, I);
    k_rowdot<<<(U + 7) / 8, 256, 0, stream>>>(Xu, U, v1, v2, t1, t2);
    k_rowdot<<<(I + 7) / 8, 256, 0, stream>>>(Xi, I, v2, v1, u1, u2);
    k_edge1<<<4096, 256, 0, stream>>>(Xu, CD, t1, t2, u1, u2, c0, adj, gu1, gu2,
                                      rows, cols, L1, L2, mx1, mx2, nnz);
    k_exp<<<2048, 256, 0, stream>>>(L1, L2, rows, cols, mx1, mx2, s1, s2, out, nnz);
    k_div<<<2048, 256, 0, stream>>>(rows, cols, s1, s2, out, nnz);
}

// Round 2
// 644.692 us; speedup vs baseline: 2.0631x; 2.0631x over previous
//
#include <hip/hip_runtime.h>
#include <hip/hip_bf16.h>

// Sparse graph-attention Gumbel mask.
//
// Restructuring: with M = Wq^T Wk [E,E],
//   w_ui[e] = adj*( Xu[r]·C[c] + t1[r] + u1[c] + c0 ),  C = Xi M^T
//   w_iu[e] = adj*( Xu[r]·D[c] + t2[r] + u2[c] + c0 ),  D = Xi M
// so the per-edge gather is Xu[r] (512B) + CD[c] (1KB) instead of 2KB of
// projected rows. t*/u*/c0 are bias-fold scalars (zero for this instance,
// implemented for generality).

#define EMB 128
#define TAUINV 2.0f

__device__ __forceinline__ unsigned fkey(float f) {
    unsigned u = __float_as_uint(f);
    return (u & 0x80000000u) ? ~u : (u | 0x80000000u);
}
__device__ __forceinline__ float fdecode(unsigned u) {
    return __uint_as_float((u & 0x80000000u) ? (u ^ 0x80000000u) : ~u);
}

// ---- kernel 1: BIGM[k][j] (j<128: M[j][k]; j>=128: M[k][j-128]), v1, v2, c0
__global__ void k_prep(const float* __restrict__ Wq, const float* __restrict__ Wk,
                       const float* __restrict__ bq, const float* __restrict__ bk,
                       float* __restrict__ BIGM, float* __restrict__ v1,
                       float* __restrict__ v2, float* __restrict__ c0) {
    int e1 = blockIdx.x, e2 = threadIdx.x;
    float acc = 0.f;
    for (int a = 0; a < EMB; ++a) acc += Wq[a * EMB + e1] * Wk[a * EMB + e2];
    // M[e1][e2] = acc
    BIGM[e2 * 256 + e1] = acc;            // BIGM[k=e2][j=e1] = M[j][k]
    BIGM[e1 * 256 + 128 + e2] = acc;      // BIGM[k=e1][128+e2] = M[k][e2]
    if (e2 == 0) { float s = 0.f; for (int a = 0; a < EMB; ++a) s += Wq[a * EMB + e1] * bk[a]; v1[e1] = s; }
    if (e2 == 1) { float s = 0.f; for (int a = 0; a < EMB; ++a) s += Wk[a * EMB + e1] * bq[a]; v2[e1] = s; }
    if (e1 == 0 && e2 == 2) { float s = 0.f; for (int a = 0; a < EMB; ++a) s += bq[a] * bk[a]; *c0 = s; }
}

// ---- kernel 2: CD[m][j] = sum_k Xi[m][k] * BIGM[k][j], j in [0,256)
// Lean mapping to avoid the R0 spill disaster: thread = 8 rows x 1 float4-col
// (acc[8] = 32 VGPR), BIGM staged in 32-k chunks (32 KB), Xi tile 16 KB.
__global__ __launch_bounds__(256) void k_cd(const float* __restrict__ Xi,
                                            const float* __restrict__ BIGM,
                                            float* __restrict__ CD, int nItems) {
    __shared__ float Xs[32][EMB];     // 16 KB: 32 item rows
    __shared__ float Ms[32][256];     // 32 KB: 32 k-rows of BIGM
    const int t = threadIdx.x;
    const int m0 = blockIdx.x * 32;

    // stage Xi tile (1024 float4)
    const float4* Xi4 = (const float4*)Xi;
    float4* Xs4 = (float4*)Xs;
    for (int idx = t; idx < 32 * 32; idx += 256) {
        int r = idx >> 5, c = idx & 31;
        int row = m0 + r;
        Xs4[idx] = (row < nItems) ? Xi4[(size_t)row * 32 + c]
                                  : make_float4(0.f, 0.f, 0.f, 0.f);
    }

    const int tc = t & 63;   // float4 column: cols 4*tc .. 4*tc+3
    const int tr = t >> 6;   // row group: rows 8*tr .. 8*tr+7
    float4 acc[8] = {};

    const float4* BG4 = (const float4*)BIGM;
    float4* Ms4 = (float4*)Ms;
    for (int kc = 0; kc < EMB; kc += 32) {
        __syncthreads();   // also covers initial Xs stage
        for (int idx = t; idx < 32 * 64; idx += 256)
            Ms4[idx] = BG4[(size_t)(kc + (idx >> 6)) * 64 + (idx & 63)];
        __syncthreads();
#pragma unroll
        for (int kk = 0; kk < 32; ++kk) {
            float4 w = Ms4[kk * 64 + tc];
#pragma unroll
            for (int i = 0; i < 8; ++i) {
                float x = Xs[tr * 8 + i][kc + kk];
                acc[i].x += x * w.x; acc[i].y += x * w.y;
                acc[i].z += x * w.z; acc[i].w += x * w.w;
            }
        }
    }
#pragma unroll
    for (int i = 0; i < 8; ++i) {
        int row = m0 + tr * 8 + i;
        if (row < nItems)
            ((float4*)(CD + (size_t)row * 256))[tc] = acc[i];
    }
}

// ---- kernel 3: o1[g] = X[g]·a, o2[g] = X[g]·b (32 lanes per row)
__global__ void k_rowdot(const float* __restrict__ X, int n,
                         const float* __restrict__ a, const float* __restrict__ b,
                         float* __restrict__ o1, float* __restrict__ o2) {
    int g = blockIdx.x * 8 + (threadIdx.x >> 5);
    int l = threadIdx.x & 31;
    if (g >= n) return;
    float4 x = ((const float4*)(X + (size_t)g * EMB))[l];
    float4 av = ((const float4*)a)[l];
    float4 bv = ((const float4*)b)[l];
    float p1 = x.x * av.x + x.y * av.y + x.z * av.z + x.w * av.w;
    float p2 = x.x * bv.x + x.y * bv.y + x.z * bv.z + x.w * bv.w;
    for (int off = 16; off; off >>= 1) { p1 += __shfl_xor(p1, off); p2 += __shfl_xor(p2, off); }
    if (l == 0) { o1[g] = p1; o2[g] = p2; }
}

// ---- kernel 4: per-edge dots, logits, segment max (32 lanes per edge)
__global__ __launch_bounds__(256) void k_edge1(
    const float* __restrict__ Xu, const float* __restrict__ CD,
    const float* __restrict__ t1, const float* __restrict__ t2,
    const float* __restrict__ u1, const float* __restrict__ u2,
    const float* __restrict__ c0p, const float* __restrict__ adj,
    const float* __restrict__ gu1, const float* __restrict__ gu2,
    const int* __restrict__ rows, const int* __restrict__ cols,
    float* __restrict__ L1, float* __restrict__ L2,
    unsigned* __restrict__ mx1, unsigned* __restrict__ mx2, int nnz) {
    const int gid = blockIdx.x * 8 + (threadIdx.x >> 5);
    const int l = threadIdx.x & 31;
    const int stride = gridDim.x * 8;
    const float c0 = *c0p;
    for (int e = gid; e < nnz; e += stride) {
        int r = rows[e], c = cols[e];
        float4 xu = ((const float4*)(Xu + (size_t)r * EMB))[l];
        const float4* cd = (const float4*)(CD + (size_t)c * 256);
        float4 cv = cd[l];
        float4 dv = cd[32 + l];
        float p1 = xu.x * cv.x + xu.y * cv.y + xu.z * cv.z + xu.w * cv.w;
        float p2 = xu.x * dv.x + xu.y * dv.y + xu.z * dv.z + xu.w * dv.w;
        for (int off = 16; off; off >>= 1) { p1 += __shfl_xor(p1, off); p2 += __shfl_xor(p2, off); }
        if (l < 2) {
            float p = (l == 0) ? p1 : p2;
            float tt = (l == 0) ? t1[r] : t2[r];
            float uu = (l == 0) ? u1[c] : u2[c];
            float g = logf(-logf(((l == 0) ? gu1 : gu2)[e]));   // logf, not __logf: u near 1 needs relative accuracy
            float w = adj[e] * (p + tt + uu + c0);
            float lg = (w - g) * TAUINV;
            if (l == 0) { L1[e] = lg; atomicMax(mx1 + r, fkey(lg)); }
            else        { L2[e] = lg; atomicMax(mx2 + c, fkey(lg)); }
        }
    }
}

// ---- kernel 5: exp(logit - max), write out, segment sums
__global__ void k_exp(const float* __restrict__ L1, const float* __restrict__ L2,
                      const int* __restrict__ rows, const int* __restrict__ cols,
                      const unsigned* __restrict__ mx1, const unsigned* __restrict__ mx2,
                      float* __restrict__ s1, float* __restrict__ s2,
                      float* __restrict__ out, int nnz) {
    int i0 = blockIdx.x * blockDim.x + threadIdx.x;
    int stride = gridDim.x * blockDim.x;
    for (int e = i0; e < nnz; e += stride) {
        int r = rows[e], c = cols[e];
        float e1 = expf(L1[e] - fdecode(mx1[r]));
        float e2 = expf(L2[e] - fdecode(mx2[c]));
        out[e] = e1;
        out[nnz + e] = e2;
        atomicAdd(s1 + r, e1);
        atomicAdd(s2 + c, e2);
    }
}

// ---- kernel 6: normalize
__global__ void k_div(const int* __restrict__ rows, const int* __restrict__ cols,
                      const float* __restrict__ s1, const float* __restrict__ s2,
                      float* __restrict__ out, int nnz) {
    int i0 = blockIdx.x * blockDim.x + threadIdx.x;
    int stride = gridDim.x * blockDim.x;
    for (int e = i0; e < nnz; e += stride) {
        out[e] = out[e] / s1[rows[e]];
        out[nnz + e] = out[nnz + e] / s2[cols[e]];
    }
}

extern "C" void kernel_launch(void* const* d_in, const int* in_sizes, int n_in,
                              void* d_out, int out_size, void* d_ws, size_t ws_size,
                              hipStream_t stream) {
    const float* Xu  = (const float*)d_in[0];
    const float* Xi  = (const float*)d_in[1];
    const float* Wq  = (const float*)d_in[2];
    const float* bq  = (const float*)d_in[3];
    const float* Wk  = (const float*)d_in[4];
    const float* bk  = (const float*)d_in[5];
    const float* adj = (const float*)d_in[6];
    const float* gu1 = (const float*)d_in[7];
    const float* gu2 = (const float*)d_in[8];
    const int* rows  = (const int*)d_in[9];
    const int* cols  = (const int*)d_in[10];
    float* out = (float*)d_out;

    const int U   = in_sizes[0] / EMB;
    const int I   = in_sizes[1] / EMB;
    const int nnz = in_sizes[6];

    float* w = (float*)d_ws;
    float* BIGM = w;                      // 128*256
    float* v1   = BIGM + 32768;           // 128
    float* v2   = v1 + 128;               // 128
    float* c0   = v2 + 128;               // 1 (padded 64)
    float* t1   = c0 + 64;                // U
    float* t2   = t1 + U;                 // U
    float* u1   = t2 + U;                 // I
    float* u2   = u1 + I;                 // I
    float* CD   = u2 + I;                 // I*256
    float* L1   = CD + (size_t)I * 256;   // nnz
    float* L2   = L1 + nnz;               // nnz
    unsigned* mx1 = (unsigned*)(L2 + nnz);   // U
    unsigned* mx2 = mx1 + U;                 // I
    float* s1   = (float*)(mx2 + I);         // U
    float* s2   = s1 + U;                    // I
    size_t need = (size_t)((char*)(s2 + I) - (char*)d_ws);
    if (need > ws_size) return;  // insufficient workspace: fail loudly

    // zero mx1/mx2/s1/s2 (contiguous). key==0 encodes -NaN: below every real key.
    hipMemsetAsync(mx1, 0, (size_t)(2 * (U + I)) * 4, stream);

    k_prep<<<128, 128, 0, stream>>>(Wq, Wk, bq, bk, BIGM, v1, v2, c0);
    k_cd<<<(I + 31) / 32, 256, 0, stream>>>(Xi, BIGM, CD, I);
    k_rowdot<<<(U + 7) / 8, 256, 0, stream>>>(Xu, U, v1, v2, t1, t2);
    k_rowdot<<<(I + 7) / 8, 256, 0, stream>>>(Xi, I, v2, v1, u1, u2);
    k_edge1<<<4096, 256, 0, stream>>>(Xu, CD, t1, t2, u1, u2, c0, adj, gu1, gu2,
                                      rows, cols, L1, L2, mx1, mx2, nnz);
    k_exp<<<2048, 256, 0, stream>>>(L1, L2, rows, cols, mx1, mx2, s1, s2, out, nnz);
    k_div<<<2048, 256, 0, stream>>>(rows, cols, s1, s2, out, nnz);
}